// Round 4
// baseline (239.708 us; speedup 1.0000x reference)
//
#include <hip/hip_runtime.h>
#include <hip/hip_bf16.h>

#define BROWS 32768
#define CDIM 1000
#define CPAD 1024
#define HDIM 128
#define NBUCK 2048          // 12-bit key: 8-bit exp + 4 mantissa bits
#define WSTRIDE 2056        // NBUCK + 8 words: staggers hot banks across the 4 waves

typedef __attribute__((ext_vector_type(8))) short short8;
typedef __attribute__((ext_vector_type(4))) float f32x4;

__device__ inline unsigned short f2bf(float x) {
    unsigned int b = __float_as_uint(x);
    unsigned int r = (b + 0x7FFFu + ((b >> 16) & 1u)) >> 16;  // RNE
    return (unsigned short)r;
}
__device__ inline float bf2f(unsigned short u) {
    return __uint_as_float(((unsigned int)u) << 16);
}

// ---------------- prep: transpose weights to [N][K] bf16, zero-padded ----------------
__global__ __launch_bounds__(256) void k_prep(const float* __restrict__ W1,
                                              const float* __restrict__ W2,
                                              const float* __restrict__ W3,
                                              unsigned short* __restrict__ W1t,
                                              unsigned short* __restrict__ W2t,
                                              unsigned short* __restrict__ W3t) {
    const int idx = blockIdx.x * 256 + threadIdx.x;  // [0, 131072)
    {   // W1t[n][k], n<128, k<1024 ; W1 is [1000][128]
        const int n = idx >> 10, k = idx & 1023;
        W1t[idx] = (k < CDIM) ? f2bf(W1[(size_t)k * HDIM + n]) : (unsigned short)0;
    }
    {   // W3t[n][k], n<1024, k<128 ; W3 is [128][1000]
        const int n = idx >> 7, k = idx & 127;
        W3t[idx] = (n < CDIM) ? f2bf(W3[(size_t)k * CDIM + n]) : (unsigned short)0;
    }
    if (idx < 16384) {  // W2t[n][k], 128x128 ; W2 is [128][128]
        const int n = idx >> 7, k = idx & 127;
        W2t[idx] = f2bf(W2[(size_t)k * HDIM + n]);
    }
}

// ---------------- softmax: one wave per row, write bf16 prob (padded to 1024) --------
__global__ __launch_bounds__(256) void k_softmax(const float* __restrict__ logits,
                                                 unsigned short* __restrict__ prob) {
    const int wv = threadIdx.x >> 6, lane = threadIdx.x & 63;
    const int row = (blockIdx.x << 2) + wv;
    const int base = lane << 4;
    const float* lrow = logits + (size_t)row * CDIM;
    float lg[16];
#pragma unroll
    for (int q = 0; q < 4; ++q) {
        const int c = base + (q << 2);
        if (c < CDIM) {
            const float4 v4 = *reinterpret_cast<const float4*>(lrow + c);
            lg[q * 4] = v4.x; lg[q * 4 + 1] = v4.y; lg[q * 4 + 2] = v4.z; lg[q * 4 + 3] = v4.w;
        } else {
            lg[q * 4] = lg[q * 4 + 1] = lg[q * 4 + 2] = lg[q * 4 + 3] = -INFINITY;
        }
    }
    float mx = lg[0];
#pragma unroll
    for (int e = 1; e < 16; ++e) mx = fmaxf(mx, lg[e]);
#pragma unroll
    for (int off = 32; off >= 1; off >>= 1) mx = fmaxf(mx, __shfl_xor(mx, off));
    float p[16], s = 0.f;
#pragma unroll
    for (int e = 0; e < 16; ++e) { p[e] = __expf(lg[e] - mx); s += p[e]; }
#pragma unroll
    for (int off = 32; off >= 1; off >>= 1) s += __shfl_xor(s, off);
    const float inv = 1.f / s;
    unsigned int w[8];
#pragma unroll
    for (int i = 0; i < 8; ++i) {
        const unsigned int lo = f2bf(p[2 * i] * inv);
        const unsigned int hi = f2bf(p[2 * i + 1] * inv);
        w[i] = lo | (hi << 16);
    }
    uint4 o0, o1;
    o0.x = w[0]; o0.y = w[1]; o0.z = w[2]; o0.w = w[3];
    o1.x = w[4]; o1.y = w[5]; o1.z = w[6]; o1.w = w[7];
    uint4* dst = reinterpret_cast<uint4*>(prob + (size_t)row * CPAD + base);
    dst[0] = o0; dst[1] = o1;
}

// ---------------- GEMM: C[M,N] = epi(A[M,K] @ Bt[N,K]^T + bias) ----------------------
// 512 threads = 8 waves (4m x 2n), block tile 128x128, BK=64, XOR-swizzled LDS chunks.
// EPI 0: relu(v + bias)   EPI 1: n==nlimit-1 ? v+bias : sigmoid(v+bias)
template <int EPI>
__global__ __launch_bounds__(512) void k_gemm(const unsigned short* __restrict__ A, int lda,
                                              const unsigned short* __restrict__ Bt, int ldb,
                                              const float* __restrict__ bias,
                                              unsigned short* __restrict__ outp, int ldo,
                                              int K, int nlimit) {
    __shared__ uint4 As[128 * 8];
    __shared__ uint4 Bs[128 * 8];
    const int tid = threadIdx.x;
    const int bm = blockIdx.x, bn = blockIdx.y;
    const int lane = tid & 63, w = tid >> 6;
    const int wm = (w >> 1) << 5;   // wave m-offset: 4 waves * 32 rows
    const int wn = (w & 1) << 6;    // wave n-offset: 2 waves * 64 cols
    const int l15 = lane & 15, l4 = lane >> 4;
    f32x4 acc[2][4] = {};

    for (int k0 = 0; k0 < K; k0 += 64) {
        __syncthreads();
#pragma unroll
        for (int i = 0; i < 2; ++i) {
            const int cid = tid + (i << 9);         // [0,1024)
            const int r = cid >> 3, c = cid & 7;    // row, 16B-chunk
            As[(r << 3) + (c ^ (r & 7))] =
                *reinterpret_cast<const uint4*>(A + (size_t)(bm * 128 + r) * lda + k0 + (c << 3));
            Bs[(r << 3) + (c ^ (r & 7))] =
                *reinterpret_cast<const uint4*>(Bt + (size_t)(bn * 128 + r) * ldb + k0 + (c << 3));
        }
        __syncthreads();
#pragma unroll
        for (int kk = 0; kk < 2; ++kk) {
            short8 a[2], b[4];
#pragma unroll
            for (int mf = 0; mf < 2; ++mf) {
                const int r = wm + (mf << 4) + l15;
                a[mf] = *reinterpret_cast<const short8*>(&As[(r << 3) + (((kk << 2) + l4) ^ (r & 7))]);
            }
#pragma unroll
            for (int nf = 0; nf < 4; ++nf) {
                const int r = wn + (nf << 4) + l15;
                b[nf] = *reinterpret_cast<const short8*>(&Bs[(r << 3) + (((kk << 2) + l4) ^ (r & 7))]);
            }
#pragma unroll
            for (int mf = 0; mf < 2; ++mf)
#pragma unroll
                for (int nf = 0; nf < 4; ++nf)
                    acc[mf][nf] = __builtin_amdgcn_mfma_f32_16x16x32_bf16(a[mf], b[nf], acc[mf][nf], 0, 0, 0);
        }
    }
    // epilogue: D frag layout col = lane&15, row = (lane>>4)*4 + r
#pragma unroll
    for (int mf = 0; mf < 2; ++mf) {
#pragma unroll
        for (int nf = 0; nf < 4; ++nf) {
            const int n = (bn << 7) + wn + (nf << 4) + l15;
            float bv;
            if (EPI == 0) bv = bias[n];
            else bv = (n < nlimit) ? bias[n] : 0.f;
#pragma unroll
            for (int r = 0; r < 4; ++r) {
                const int m = (bm << 7) + wm + (mf << 4) + (l4 << 2) + r;
                float v = acc[mf][nf][r] + bv;
                if (EPI == 0) {
                    v = fmaxf(v, 0.f);
                } else {
                    if (n != nlimit - 1) v = 1.f / (1.f + __expf(-v));
                }
                outp[(size_t)m * ldo + n] = f2bf(v);
            }
        }
    }
}

// ---------------- sort + finish: counting sort v3, one wave per row --------------------
// 12-bit monotone key (top 12 bits of fp32 prob, key <= 2032 < 2048). Single atomic
// pass: atomicAdd return = stable in-bucket offset; after suffix-scan of the histogram,
// rank = start[key] + offset. Unified per-wave histogram (same-address collisions only;
// a 2-way addr split made it WORSE in round 3 — same bank). Per-wave LDS region stride
// 2056 words staggers hot buckets across banks between the 4 waves of a block.
// Region reuse: [0..2047] hist -> start table -> (0..1023 sortedp, 1024..2047 Sarr).
// All accesses via one u32 pointer; all ordering is within-wave -> zero barriers.
__global__ __launch_bounds__(256) void k_sortfinish(const float* __restrict__ logits,
                                                    const unsigned short* __restrict__ cal,
                                                    float* __restrict__ out) {
    __shared__ unsigned int shm[4 * WSTRIDE];
    const int wv = threadIdx.x >> 6, lane = threadIdx.x & 63;
    const int row = (blockIdx.x << 2) + wv;
    unsigned int* sm = &shm[wv * WSTRIDE];
    const int base = lane << 4;

    // zero histogram (2048 words, 32/lane)
    {
        uint4 z; z.x = 0; z.y = 0; z.z = 0; z.w = 0;
        const int zb = lane << 5;
#pragma unroll
        for (int q = 0; q < 8; ++q)
            *reinterpret_cast<uint4*>(&sm[zb + (q << 2)]) = z;
    }

    // ---- load logits + softmax (fp32) ----
    const float* lrow = logits + (size_t)row * CDIM;
    float lg[16];
#pragma unroll
    for (int q = 0; q < 4; ++q) {
        const int c = base + (q << 2);
        if (c < CDIM) {
            const float4 v4 = *reinterpret_cast<const float4*>(lrow + c);
            lg[q * 4] = v4.x; lg[q * 4 + 1] = v4.y; lg[q * 4 + 2] = v4.z; lg[q * 4 + 3] = v4.w;
        } else {
            lg[q * 4] = lg[q * 4 + 1] = lg[q * 4 + 2] = lg[q * 4 + 3] = -INFINITY;
        }
    }
    // hoist cal row loads: HBM latency overlaps the atomic phase below
    const unsigned short* crow = cal + (size_t)row * CPAD + base;
    const uint4 c0v = *reinterpret_cast<const uint4*>(crow);
    const uint4 c1v = *reinterpret_cast<const uint4*>(crow + 8);

    float mx = lg[0];
#pragma unroll
    for (int e = 1; e < 16; ++e) mx = fmaxf(mx, lg[e]);
#pragma unroll
    for (int off = 32; off >= 1; off >>= 1) mx = fmaxf(mx, __shfl_xor(mx, off));
    float p[16], s = 0.f;
#pragma unroll
    for (int e = 0; e < 16; ++e) { p[e] = __expf(lg[e] - mx); s += p[e]; }
#pragma unroll
    for (int off = 32; off >= 1; off >>= 1) s += __shfl_xor(s, off);
    const float inv = 1.f / s;
#pragma unroll
    for (int e = 0; e < 16; ++e) p[e] *= inv;

    // ---- single atomic pass: histogram count + stable in-bucket offset ----
    unsigned int key[16], offv[16];
#pragma unroll
    for (int e = 0; e < 16; ++e) {
        key[e] = __float_as_uint(p[e]) >> 19;   // 12-bit monotone key, <= 2032
        offv[e] = (base + e < CDIM) ? atomicAdd(&sm[key[e]], 1u) : 0u;
    }

    // ---- bucket suffix-scan: start[b] = sum_{b' > b} cnt[b'] (descending ranks) ----
    {
        unsigned int c16[32];
        const int sb = lane << 5;   // lane owns buckets [32*lane, 32*lane+32)
#pragma unroll
        for (int q = 0; q < 8; ++q) {
            const uint4 v4 = *reinterpret_cast<const uint4*>(&sm[sb + (q << 2)]);
            c16[q * 4] = v4.x; c16[q * 4 + 1] = v4.y; c16[q * 4 + 2] = v4.z; c16[q * 4 + 3] = v4.w;
        }
        unsigned int lsum = 0;
#pragma unroll
        for (int e = 0; e < 32; ++e) lsum += c16[e];
        // inclusive suffix over lanes
        unsigned int suf = lsum;
#pragma unroll
        for (int off = 1; off < 64; off <<= 1) {
            const unsigned int u = __shfl_down(suf, off);
            if (lane + off < 64) suf += u;
        }
        unsigned int run = suf - lsum;  // sum over lanes > this lane
        unsigned int st[32];
#pragma unroll
        for (int e = 31; e >= 0; --e) { st[e] = run; run += c16[e]; }
#pragma unroll
        for (int q = 0; q < 8; ++q) {
            uint4 v4;
            v4.x = st[q * 4]; v4.y = st[q * 4 + 1]; v4.z = st[q * 4 + 2]; v4.w = st[q * 4 + 3];
            *reinterpret_cast<uint4*>(&sm[sb + (q << 2)]) = v4;
        }
    }

    // ---- rank = start[key] + offset (same-address reads broadcast: cheap) ----
    int rk[16];
#pragma unroll
    for (int e = 0; e < 16; ++e)
        rk[e] = (base + e < CDIM) ? (int)(sm[key[e]] + offv[e]) : 1023;

    // ---- scatter full-precision probs to rank order (reuse [0..1023]) ----
#pragma unroll
    for (int e = 0; e < 16; ++e)
        if (base + e < CDIM) sm[rk[e]] = __float_as_uint(p[e]);

    // ---- rank-space: v[r] = (sp[r]-sp[r+1])*cal[r], r<999; v[999]=cal[999]; else 0 ----
    float sp[16];
#pragma unroll
    for (int q = 0; q < 4; ++q) {
        const uint4 v4 = *reinterpret_cast<const uint4*>(&sm[base + (q << 2)]);
        sp[q * 4] = __uint_as_float(v4.x); sp[q * 4 + 1] = __uint_as_float(v4.y);
        sp[q * 4 + 2] = __uint_as_float(v4.z); sp[q * 4 + 3] = __uint_as_float(v4.w);
    }
    const float spn_next = __shfl_down(sp[0], 1);
    const unsigned int cw[8] = {c0v.x, c0v.y, c0v.z, c0v.w, c1v.x, c1v.y, c1v.z, c1v.w};
    float v[16];
#pragma unroll
    for (int e = 0; e < 16; ++e) {
        const int r = base + e;
        const float cv = bf2f((unsigned short)((cw[e >> 1] >> ((e & 1) * 16)) & 0xFFFFu));
        const float spn = (e < 15) ? sp[e + 1] : spn_next;
        float val;
        if (r < CDIM - 1) val = (sp[e] - spn) * cv;
        else if (r == CDIM - 1) val = cv;
        else val = 0.f;
        v[e] = val;
    }
    // suffix sum over rank space
    float lsuf[16], run = 0.f;
#pragma unroll
    for (int e = 15; e >= 0; --e) { run += v[e]; lsuf[e] = run; }
    float pi = run;
#pragma unroll
    for (int off = 1; off < 64; off <<= 1) {
        const float u = __shfl_up(pi, off);
        if (lane >= off) pi += u;
    }
    const float tot = __shfl(pi, 63);
    const float after = tot - pi;  // sum over lanes > this lane
#pragma unroll
    for (int q = 0; q < 4; ++q) {
        uint4 v4;
        v4.x = __float_as_uint(lsuf[q * 4] + after);
        v4.y = __float_as_uint(lsuf[q * 4 + 1] + after);
        v4.z = __float_as_uint(lsuf[q * 4 + 2] + after);
        v4.w = __float_as_uint(lsuf[q * 4 + 3] + after);
        *reinterpret_cast<uint4*>(&sm[1024 + base + (q << 2)]) = v4;  // Sarr
    }

    // ---- gather fitted by rank, add logits, store ----
    float f[16];
#pragma unroll
    for (int e = 0; e < 16; ++e) f[e] = __uint_as_float(sm[1024 + rk[e]]);
#pragma unroll
    for (int q = 0; q < 4; ++q) {
        const int c = base + (q << 2);
        if (c < CDIM) {
            float4 o;
            o.x = lg[q * 4] + f[q * 4];
            o.y = lg[q * 4 + 1] + f[q * 4 + 1];
            o.z = lg[q * 4 + 2] + f[q * 4 + 2];
            o.w = lg[q * 4 + 3] + f[q * 4 + 3];
            *reinterpret_cast<float4*>(out + (size_t)row * CDIM + c) = o;
        }
    }
}

// ---------------- host ----------------
extern "C" void kernel_launch(void* const* d_in, const int* in_sizes, int n_in,
                              void* d_out, int out_size, void* d_ws, size_t ws_size,
                              hipStream_t stream) {
    const float* logits = (const float*)d_in[0];
    const float* W1 = (const float*)d_in[1];
    const float* b1 = (const float*)d_in[2];
    const float* W2 = (const float*)d_in[3];
    const float* b2 = (const float*)d_in[4];
    const float* W3 = (const float*)d_in[5];
    const float* b3 = (const float*)d_in[6];
    float* out = (float*)d_out;

    char* ws = (char*)d_ws;
    unsigned short* prob = (unsigned short*)ws;                    // 32768*1024*2 = 64 MB
    unsigned short* h1   = (unsigned short*)(ws + 67108864);       // 8 MB
    unsigned short* h2   = (unsigned short*)(ws + 75497472);       // 8 MB
    unsigned short* W1t  = (unsigned short*)(ws + 83886080);       // 256 KB
    unsigned short* W2t  = (unsigned short*)(ws + 84148224);       // 32 KB
    unsigned short* W3t  = (unsigned short*)(ws + 84180992);       // 256 KB
    unsigned short* cal  = prob;  // reuse: prob dead after GEMM1, cal written by GEMM3

    k_prep<<<512, 256, 0, stream>>>(W1, W2, W3, W1t, W2t, W3t);
    k_softmax<<<BROWS / 4, 256, 0, stream>>>(logits, prob);
    k_gemm<0><<<dim3(BROWS / 128, 1), 512, 0, stream>>>(prob, CPAD, W1t, CPAD, b1, h1, HDIM, CPAD, 0);
    k_gemm<0><<<dim3(BROWS / 128, 1), 512, 0, stream>>>(h1, HDIM, W2t, HDIM, b2, h2, HDIM, HDIM, 0);
    k_gemm<1><<<dim3(BROWS / 128, 8), 512, 0, stream>>>(h2, HDIM, W3t, HDIM, b3, cal, CPAD, HDIM, CDIM);
    k_sortfinish<<<BROWS / 4, 256, 0, stream>>>(logits, cal, out);
}

// Round 5
// 177.778 us; speedup vs baseline: 1.3484x; 1.3484x over previous
//
#include <hip/hip_runtime.h>
#include <hip/hip_bf16.h>

#define BROWS 32768
#define CDIM 1000
#define CPAD 1024
#define HDIM 128
#define REG 1056            // PHYS(1023)+2, padded per-array region (words)
#define WST  (2 * REG)      // per-wave LDS: region A (hist/start/Sarr) + region B (sortedp)
#define PHYS(i) ((i) + ((i) >> 5))   // +1 pad word per 32: kills 64B-stride bank aliasing

typedef __attribute__((ext_vector_type(8))) short short8;
typedef __attribute__((ext_vector_type(4))) float f32x4;

__device__ inline unsigned short f2bf(float x) {
    unsigned int b = __float_as_uint(x);
    unsigned int r = (b + 0x7FFFu + ((b >> 16) & 1u)) >> 16;  // RNE
    return (unsigned short)r;
}
__device__ inline float bf2f(unsigned short u) {
    return __uint_as_float(((unsigned int)u) << 16);
}

// ---------------- prep: transpose weights to [N][K] bf16, zero-padded ----------------
__global__ __launch_bounds__(256) void k_prep(const float* __restrict__ W1,
                                              const float* __restrict__ W2,
                                              const float* __restrict__ W3,
                                              unsigned short* __restrict__ W1t,
                                              unsigned short* __restrict__ W2t,
                                              unsigned short* __restrict__ W3t) {
    const int idx = blockIdx.x * 256 + threadIdx.x;  // [0, 131072)
    {   // W1t[n][k], n<128, k<1024 ; W1 is [1000][128]
        const int n = idx >> 10, k = idx & 1023;
        W1t[idx] = (k < CDIM) ? f2bf(W1[(size_t)k * HDIM + n]) : (unsigned short)0;
    }
    {   // W3t[n][k], n<1024, k<128 ; W3 is [128][1000]
        const int n = idx >> 7, k = idx & 127;
        W3t[idx] = (n < CDIM) ? f2bf(W3[(size_t)k * CDIM + n]) : (unsigned short)0;
    }
    if (idx < 16384) {  // W2t[n][k], 128x128 ; W2 is [128][128]
        const int n = idx >> 7, k = idx & 127;
        W2t[idx] = f2bf(W2[(size_t)k * HDIM + n]);
    }
}

// ---------------- softmax: one wave per row, write bf16 prob (padded to 1024) --------
__global__ __launch_bounds__(256) void k_softmax(const float* __restrict__ logits,
                                                 unsigned short* __restrict__ prob) {
    const int wv = threadIdx.x >> 6, lane = threadIdx.x & 63;
    const int row = (blockIdx.x << 2) + wv;
    const int base = lane << 4;
    const float* lrow = logits + (size_t)row * CDIM;
    float lg[16];
#pragma unroll
    for (int q = 0; q < 4; ++q) {
        const int c = base + (q << 2);
        if (c < CDIM) {
            const float4 v4 = *reinterpret_cast<const float4*>(lrow + c);
            lg[q * 4] = v4.x; lg[q * 4 + 1] = v4.y; lg[q * 4 + 2] = v4.z; lg[q * 4 + 3] = v4.w;
        } else {
            lg[q * 4] = lg[q * 4 + 1] = lg[q * 4 + 2] = lg[q * 4 + 3] = -INFINITY;
        }
    }
    float mx = lg[0];
#pragma unroll
    for (int e = 1; e < 16; ++e) mx = fmaxf(mx, lg[e]);
#pragma unroll
    for (int off = 32; off >= 1; off >>= 1) mx = fmaxf(mx, __shfl_xor(mx, off));
    float p[16], s = 0.f;
#pragma unroll
    for (int e = 0; e < 16; ++e) { p[e] = __expf(lg[e] - mx); s += p[e]; }
#pragma unroll
    for (int off = 32; off >= 1; off >>= 1) s += __shfl_xor(s, off);
    const float inv = 1.f / s;
    unsigned int w[8];
#pragma unroll
    for (int i = 0; i < 8; ++i) {
        const unsigned int lo = f2bf(p[2 * i] * inv);
        const unsigned int hi = f2bf(p[2 * i + 1] * inv);
        w[i] = lo | (hi << 16);
    }
    uint4 o0, o1;
    o0.x = w[0]; o0.y = w[1]; o0.z = w[2]; o0.w = w[3];
    o1.x = w[4]; o1.y = w[5]; o1.z = w[6]; o1.w = w[7];
    uint4* dst = reinterpret_cast<uint4*>(prob + (size_t)row * CPAD + base);
    dst[0] = o0; dst[1] = o1;
}

// ---------------- GEMM: C[M,N] = epi(A[M,K] @ Bt[N,K]^T + bias) ----------------------
// 512 threads = 8 waves (4m x 2n), block tile 128x128, BK=64, XOR-swizzled LDS chunks.
// EPI 0: relu(v + bias)   EPI 1: n==nlimit-1 ? v+bias : sigmoid(v+bias)
template <int EPI>
__global__ __launch_bounds__(512) void k_gemm(const unsigned short* __restrict__ A, int lda,
                                              const unsigned short* __restrict__ Bt, int ldb,
                                              const float* __restrict__ bias,
                                              unsigned short* __restrict__ outp, int ldo,
                                              int K, int nlimit) {
    __shared__ uint4 As[128 * 8];
    __shared__ uint4 Bs[128 * 8];
    const int tid = threadIdx.x;
    const int bm = blockIdx.x, bn = blockIdx.y;
    const int lane = tid & 63, w = tid >> 6;
    const int wm = (w >> 1) << 5;   // wave m-offset: 4 waves * 32 rows
    const int wn = (w & 1) << 6;    // wave n-offset: 2 waves * 64 cols
    const int l15 = lane & 15, l4 = lane >> 4;
    f32x4 acc[2][4] = {};

    for (int k0 = 0; k0 < K; k0 += 64) {
        __syncthreads();
#pragma unroll
        for (int i = 0; i < 2; ++i) {
            const int cid = tid + (i << 9);         // [0,1024)
            const int r = cid >> 3, c = cid & 7;    // row, 16B-chunk
            As[(r << 3) + (c ^ (r & 7))] =
                *reinterpret_cast<const uint4*>(A + (size_t)(bm * 128 + r) * lda + k0 + (c << 3));
            Bs[(r << 3) + (c ^ (r & 7))] =
                *reinterpret_cast<const uint4*>(Bt + (size_t)(bn * 128 + r) * ldb + k0 + (c << 3));
        }
        __syncthreads();
#pragma unroll
        for (int kk = 0; kk < 2; ++kk) {
            short8 a[2], b[4];
#pragma unroll
            for (int mf = 0; mf < 2; ++mf) {
                const int r = wm + (mf << 4) + l15;
                a[mf] = *reinterpret_cast<const short8*>(&As[(r << 3) + (((kk << 2) + l4) ^ (r & 7))]);
            }
#pragma unroll
            for (int nf = 0; nf < 4; ++nf) {
                const int r = wn + (nf << 4) + l15;
                b[nf] = *reinterpret_cast<const short8*>(&Bs[(r << 3) + (((kk << 2) + l4) ^ (r & 7))]);
            }
#pragma unroll
            for (int mf = 0; mf < 2; ++mf)
#pragma unroll
                for (int nf = 0; nf < 4; ++nf)
                    acc[mf][nf] = __builtin_amdgcn_mfma_f32_16x16x32_bf16(a[mf], b[nf], acc[mf][nf], 0, 0, 0);
        }
    }
    // epilogue: D frag layout col = lane&15, row = (lane>>4)*4 + r
#pragma unroll
    for (int mf = 0; mf < 2; ++mf) {
#pragma unroll
        for (int nf = 0; nf < 4; ++nf) {
            const int n = (bn << 7) + wn + (nf << 4) + l15;
            float bv;
            if (EPI == 0) bv = bias[n];
            else bv = (n < nlimit) ? bias[n] : 0.f;
#pragma unroll
            for (int r = 0; r < 4; ++r) {
                const int m = (bm << 7) + wm + (mf << 4) + (l4 << 2) + r;
                float v = acc[mf][nf][r] + bv;
                if (EPI == 0) {
                    v = fmaxf(v, 0.f);
                } else {
                    if (n != nlimit - 1) v = 1.f / (1.f + __expf(-v));
                }
                outp[(size_t)m * ldo + n] = f2bf(v);
            }
        }
    }
}

// ---------------- sort + finish: counting sort v4, one wave per row --------------------
// 11-bit monotone key (top bits of fp32 prob, key <= 1016). Single atomic pass
// (atomicAdd return = stable in-bucket offset); suffix-scan of histogram; rank =
// start[key] + offset.
// BANK FIX (this round): every per-wave LDS index goes through PHYS(i)=i+(i>>5).
// Blocked access i=16L+e then has bank (16L+L/2+e)%32 -> exactly 2 lanes/bank = free
// (was: 64B stride -> 32-way conflict on every streaming b128, the real cost in r2-r4).
// All LDS accesses are ds_read/write_b32 with the e-offset as immediate.
// Region A: hist -> start table -> Sarr (suffix sums). Region B: sorted probs.
// All ordering is within-wave -> zero barriers.
__global__ __launch_bounds__(256) void k_sortfinish(const float* __restrict__ logits,
                                                    const unsigned short* __restrict__ cal,
                                                    float* __restrict__ out) {
    __shared__ unsigned int shm[4 * WST];
    const int wv = threadIdx.x >> 6, lane = threadIdx.x & 63;
    const int row = (blockIdx.x << 2) + wv;
    unsigned int* smA = &shm[wv * WST];
    unsigned int* smB = smA + REG;
    const int base = lane << 4;
    const int pb = base + (lane >> 1);   // PHYS(base + e) == pb + e  for e in [0,16)

    // zero histogram images PHYS(0..1023)  (16 words/lane, conflict-free)
#pragma unroll
    for (int e = 0; e < 16; ++e) smA[pb + e] = 0u;

    // ---- load logits (+ hoist cal row: HBM latency overlaps atomic phase) ----
    const float* lrow = logits + (size_t)row * CDIM;
    float lg[16];
#pragma unroll
    for (int q = 0; q < 4; ++q) {
        const int c = base + (q << 2);
        if (c < CDIM) {
            const float4 v4 = *reinterpret_cast<const float4*>(lrow + c);
            lg[q * 4] = v4.x; lg[q * 4 + 1] = v4.y; lg[q * 4 + 2] = v4.z; lg[q * 4 + 3] = v4.w;
        } else {
            lg[q * 4] = lg[q * 4 + 1] = lg[q * 4 + 2] = lg[q * 4 + 3] = -INFINITY;
        }
    }
    const unsigned short* crow = cal + (size_t)row * CPAD + base;
    const uint4 c0v = *reinterpret_cast<const uint4*>(crow);
    const uint4 c1v = *reinterpret_cast<const uint4*>(crow + 8);

    // ---- softmax (fp32) ----
    float mx = lg[0];
#pragma unroll
    for (int e = 1; e < 16; ++e) mx = fmaxf(mx, lg[e]);
#pragma unroll
    for (int off = 32; off >= 1; off >>= 1) mx = fmaxf(mx, __shfl_xor(mx, off));
    float p[16], s = 0.f;
#pragma unroll
    for (int e = 0; e < 16; ++e) { p[e] = __expf(lg[e] - mx); s += p[e]; }
#pragma unroll
    for (int off = 32; off >= 1; off >>= 1) s += __shfl_xor(s, off);
    const float inv = 1.f / s;
#pragma unroll
    for (int e = 0; e < 16; ++e) p[e] *= inv;

    // ---- single atomic pass: histogram count + stable in-bucket offset ----
    unsigned int key[16], offv[16];
#pragma unroll
    for (int e = 0; e < 16; ++e) {
        key[e] = __float_as_uint(p[e]) >> 20;   // 11-bit monotone key, <= 1016
        offv[e] = (base + e < CDIM) ? atomicAdd(&smA[PHYS(key[e])], 1u) : 0u;
    }

    // ---- bucket suffix-scan: start[b] = sum_{b' > b} cnt[b'] (descending ranks) ----
    {
        unsigned int c16[16];
#pragma unroll
        for (int e = 0; e < 16; ++e) c16[e] = smA[pb + e];
        unsigned int lsum = 0;
#pragma unroll
        for (int e = 0; e < 16; ++e) lsum += c16[e];
        // inclusive suffix over lanes
        unsigned int suf = lsum;
#pragma unroll
        for (int off = 1; off < 64; off <<= 1) {
            const unsigned int u = __shfl_down(suf, off);
            if (lane + off < 64) suf += u;
        }
        unsigned int run = suf - lsum;  // sum over lanes > this lane
        unsigned int st[16];
#pragma unroll
        for (int e = 15; e >= 0; --e) { st[e] = run; run += c16[e]; }
#pragma unroll
        for (int e = 0; e < 16; ++e) smA[pb + e] = st[e];
    }

    // ---- rank = start[key] + offset (same-address reads broadcast: cheap) ----
    int rk[16];
#pragma unroll
    for (int e = 0; e < 16; ++e)
        rk[e] = (base + e < CDIM) ? (int)(smA[PHYS(key[e])] + offv[e]) : 1023;

    // ---- scatter full-precision probs to rank order (region B) ----
#pragma unroll
    for (int e = 0; e < 16; ++e)
        if (base + e < CDIM) smB[PHYS(rk[e])] = __float_as_uint(p[e]);

    // ---- rank-space: v[r] = (sp[r]-sp[r+1])*cal[r], r<999; v[999]=cal[999]; else 0 ----
    float sp[16];
#pragma unroll
    for (int e = 0; e < 16; ++e) sp[e] = __uint_as_float(smB[pb + e]);
    const float spn_next = __shfl_down(sp[0], 1);
    const unsigned int cw[8] = {c0v.x, c0v.y, c0v.z, c0v.w, c1v.x, c1v.y, c1v.z, c1v.w};
    float v[16];
#pragma unroll
    for (int e = 0; e < 16; ++e) {
        const int r = base + e;
        const float cv = bf2f((unsigned short)((cw[e >> 1] >> ((e & 1) * 16)) & 0xFFFFu));
        const float spn = (e < 15) ? sp[e + 1] : spn_next;
        float val;
        if (r < CDIM - 1) val = (sp[e] - spn) * cv;
        else if (r == CDIM - 1) val = cv;
        else val = 0.f;
        v[e] = val;
    }
    // suffix sum over rank space
    float lsuf[16], run = 0.f;
#pragma unroll
    for (int e = 15; e >= 0; --e) { run += v[e]; lsuf[e] = run; }
    float pi = run;
#pragma unroll
    for (int off = 1; off < 64; off <<= 1) {
        const float u = __shfl_up(pi, off);
        if (lane >= off) pi += u;
    }
    const float tot = __shfl(pi, 63);
    const float after = tot - pi;  // sum over lanes > this lane

    // ---- Sarr into region A (start table dead), then gather by rank ----
#pragma unroll
    for (int e = 0; e < 16; ++e) smA[pb + e] = __float_as_uint(lsuf[e] + after);
    float f[16];
#pragma unroll
    for (int e = 0; e < 16; ++e) f[e] = __uint_as_float(smA[PHYS(rk[e])]);
#pragma unroll
    for (int q = 0; q < 4; ++q) {
        const int c = base + (q << 2);
        if (c < CDIM) {
            float4 o;
            o.x = lg[q * 4] + f[q * 4];
            o.y = lg[q * 4 + 1] + f[q * 4 + 1];
            o.z = lg[q * 4 + 2] + f[q * 4 + 2];
            o.w = lg[q * 4 + 3] + f[q * 4 + 3];
            *reinterpret_cast<float4*>(out + (size_t)row * CDIM + c) = o;
        }
    }
}

// ---------------- host ----------------
extern "C" void kernel_launch(void* const* d_in, const int* in_sizes, int n_in,
                              void* d_out, int out_size, void* d_ws, size_t ws_size,
                              hipStream_t stream) {
    const float* logits = (const float*)d_in[0];
    const float* W1 = (const float*)d_in[1];
    const float* b1 = (const float*)d_in[2];
    const float* W2 = (const float*)d_in[3];
    const float* b2 = (const float*)d_in[4];
    const float* W3 = (const float*)d_in[5];
    const float* b3 = (const float*)d_in[6];
    float* out = (float*)d_out;

    char* ws = (char*)d_ws;
    unsigned short* prob = (unsigned short*)ws;                    // 32768*1024*2 = 64 MB
    unsigned short* h1   = (unsigned short*)(ws + 67108864);       // 8 MB
    unsigned short* h2   = (unsigned short*)(ws + 75497472);       // 8 MB
    unsigned short* W1t  = (unsigned short*)(ws + 83886080);       // 256 KB
    unsigned short* W2t  = (unsigned short*)(ws + 84148224);       // 32 KB
    unsigned short* W3t  = (unsigned short*)(ws + 84180992);       // 256 KB
    unsigned short* cal  = prob;  // reuse: prob dead after GEMM1, cal written by GEMM3

    k_prep<<<512, 256, 0, stream>>>(W1, W2, W3, W1t, W2t, W3t);
    k_softmax<<<BROWS / 4, 256, 0, stream>>>(logits, prob);
    k_gemm<0><<<dim3(BROWS / 128, 1), 512, 0, stream>>>(prob, CPAD, W1t, CPAD, b1, h1, HDIM, CPAD, 0);
    k_gemm<0><<<dim3(BROWS / 128, 1), 512, 0, stream>>>(h1, HDIM, W2t, HDIM, b2, h2, HDIM, HDIM, 0);
    k_gemm<1><<<dim3(BROWS / 128, 8), 512, 0, stream>>>(h2, HDIM, W3t, HDIM, b3, cal, CPAD, HDIM, CDIM);
    k_sortfinish<<<BROWS / 4, 256, 0, stream>>>(logits, cal, out);
}